// Round 7
// baseline (572.779 us; speedup 1.0000x reference)
//
#include <hip/hip_runtime.h>
#include <hip/hip_bf16.h>

// Problem constants
#define C_CLASS 64
#define C_GROUPS 8
#define C_GSIZE 32
#define C_D 2048      // IN_CH
#define C_O 256       // OUT_CH
#define C_P 5         // NUM_PROTO
#define C_M (C_CLASS*C_GROUPS*C_GSIZE)   // 16384 rows of feats

typedef __bf16 bf16;
typedef bf16 bf16x8 __attribute__((ext_vector_type(8)));
typedef bf16 bf16x4 __attribute__((ext_vector_type(4)));
typedef float floatx4 __attribute__((ext_vector_type(4)));

// async 16B global->LDS (LDS dest must be wave-uniform base + lane*16)
__device__ __forceinline__ void gl_lds16(const bf16* g, bf16* l) {
    __builtin_amdgcn_global_load_lds(
        (const __attribute__((address_space(1))) void*)g,
        (__attribute__((address_space(3))) void*)l, 16, 0, 0);
}

// ---------------- merged fp32 -> bf16 conversion: X, T, W1, Wi1 ----------------
__global__ __launch_bounds__(256) void convw_kernel(const float* __restrict__ X,
                                                    const float* __restrict__ T,
                                                    const float* __restrict__ W1,
                                                    const float* __restrict__ Wi1,
                                                    bf16* __restrict__ Xb,
                                                    bf16* __restrict__ Tb,
                                                    bf16* __restrict__ W1b,
                                                    bf16* __restrict__ Wi1b) {
    const int nX = C_M * C_D / 4;        // 8388608
    const int nT = C_D * C_D / 4;        // 1048576
    const int nW = C_O * C_D / 4;        // 131072
    int i = blockIdx.x * 256 + threadIdx.x;
    const float* s; bf16* d; int j;
    if (i < nX)                { s = X;   d = Xb;   j = i; }
    else if (i < nX + nT)      { s = T;   d = Tb;   j = i - nX; }
    else if (i < nX + nT + nW) { s = W1;  d = W1b;  j = i - nX - nT; }
    else                       { s = Wi1; d = Wi1b; j = i - nX - nT - nW; }
    float4 v = ((const float4*)s)[j];
    bf16x4 b;
    b[0] = (bf16)v.x; b[1] = (bf16)v.y; b[2] = (bf16)v.z; b[3] = (bf16)v.w;
    ((bf16x4*)d)[j] = b;
}

// ---------------- big GEMM: Yb = bf16(residb + relu(ctx . T^T)) ----------------
// (R5/R6-verified: BK=64 XOR-swizzle, GROUP_M=8 raster, 808 TF)
__global__ __launch_bounds__(256) void gemm_relu(const bf16* __restrict__ A,
                                                 const bf16* __restrict__ B,
                                                 const bf16* __restrict__ residb,
                                                 bf16* __restrict__ Cb) {
    __shared__ bf16 sA[128 * 64];
    __shared__ bf16 sB[128 * 64];

    const int tid = threadIdx.x;
    const int id  = blockIdx.x;
    const int grp = id >> 7;
    const int rem = id & 127;
    const int m0  = ((grp << 3) + (rem & 7)) << 7;
    const int n0  = (rem >> 3) << 7;

    const int lane = tid & 63;
    const int wave = tid >> 6;
    const int wm   = (wave >> 1) * 64;
    const int wn   = (wave & 1) * 64;

    const int r0 = tid >> 3;
    const int cw = (tid & 7) ^ (r0 & 7);
    const bf16* aP = A + (long)(m0 + r0) * C_D + cw * 8;
    const bf16* bP = B + (long)(n0 + r0) * C_D + cw * 8;

    floatx4 acc[4][4];
#pragma unroll
    for (int i = 0; i < 4; i++)
#pragma unroll
        for (int j = 0; j < 4; j++) acc[i][j] = (floatx4){0.f, 0.f, 0.f, 0.f};

    const int rr  = lane & 15;
    const int q   = lane >> 4;
    const int swz = lane & 7;
    const int co0 = (q ^ swz) * 8;
    const int co1 = ((q + 4) ^ swz) * 8;

    for (int k0 = 0; k0 < C_D; k0 += 64) {
        __syncthreads();
#pragma unroll
        for (int s = 0; s < 4; s++) {
            gl_lds16(aP + (long)(32 * s) * C_D + k0, &sA[(tid + 256 * s) * 8]);
            gl_lds16(bP + (long)(32 * s) * C_D + k0, &sB[(tid + 256 * s) * 8]);
        }
        __syncthreads();

#pragma unroll
        for (int kh = 0; kh < 2; kh++) {
            const int co = kh ? co1 : co0;
            bf16x8 af[4], bff[4];
#pragma unroll
            for (int i = 0; i < 4; i++) {
                af[i]  = *(const bf16x8*)&sA[(wm + i * 16 + rr) * 64 + co];
                bff[i] = *(const bf16x8*)&sB[(wn + i * 16 + rr) * 64 + co];
            }
#pragma unroll
            for (int i = 0; i < 4; i++)
#pragma unroll
                for (int j = 0; j < 4; j++)
                    acc[i][j] = __builtin_amdgcn_mfma_f32_16x16x32_bf16(af[i], bff[j], acc[i][j], 0, 0, 0);
        }
    }

    const int cn    = lane & 15;
    const int rbase = (lane >> 4) * 4;
#pragma unroll
    for (int i = 0; i < 4; i++) {
#pragma unroll
        for (int j = 0; j < 4; j++) {
            int gn = n0 + wn + j * 16 + cn;
#pragma unroll
            for (int r = 0; r < 4; r++) {
                int gm = m0 + wm + i * 16 + rbase + r;
                long idx = (long)gm * C_D + gn;
                Cb[idx] = (bf16)((float)residb[idx] + fmaxf(acc[i][j][r], 0.f));
            }
        }
    }
}

// ---------------- 64x128 NT GEMM (bf16 A/B, N=256, K=2048), fp32 out ----------------
__global__ __launch_bounds__(256) void gemm64(const bf16* __restrict__ A,
                                              const bf16* __restrict__ B,
                                              float* __restrict__ Cf) {
    __shared__ bf16 sA[64 * 64];
    __shared__ bf16 sB[128 * 64];

    const int tid  = threadIdx.x;
    const int m0   = blockIdx.x * 64;
    const int n0   = blockIdx.y * 128;
    const int lane = tid & 63;
    const int wave = tid >> 6;
    const int wm   = (wave >> 1) * 32;
    const int wn   = (wave & 1) * 64;

    const int r0 = tid >> 3;
    const int cw = (tid & 7) ^ (r0 & 7);
    const bf16* aP = A + (long)(m0 + r0) * C_D + cw * 8;
    const bf16* bP = B + (long)(n0 + r0) * C_D + cw * 8;

    floatx4 acc[2][4];
#pragma unroll
    for (int i = 0; i < 2; i++)
#pragma unroll
        for (int j = 0; j < 4; j++) acc[i][j] = (floatx4){0.f, 0.f, 0.f, 0.f};

    const int rr  = lane & 15;
    const int q   = lane >> 4;
    const int swz = lane & 7;
    const int co0 = (q ^ swz) * 8;
    const int co1 = ((q + 4) ^ swz) * 8;

    for (int k0 = 0; k0 < C_D; k0 += 64) {
        __syncthreads();
#pragma unroll
        for (int s = 0; s < 2; s++)
            gl_lds16(aP + (long)(32 * s) * C_D + k0, &sA[(tid + 256 * s) * 8]);
#pragma unroll
        for (int s = 0; s < 4; s++)
            gl_lds16(bP + (long)(32 * s) * C_D + k0, &sB[(tid + 256 * s) * 8]);
        __syncthreads();

#pragma unroll
        for (int kh = 0; kh < 2; kh++) {
            const int co = kh ? co1 : co0;
            bf16x8 af[2], bff[4];
#pragma unroll
            for (int i = 0; i < 2; i++)
                af[i] = *(const bf16x8*)&sA[(wm + i * 16 + rr) * 64 + co];
#pragma unroll
            for (int j = 0; j < 4; j++)
                bff[j] = *(const bf16x8*)&sB[(wn + j * 16 + rr) * 64 + co];
#pragma unroll
            for (int i = 0; i < 2; i++)
#pragma unroll
                for (int j = 0; j < 4; j++)
                    acc[i][j] = __builtin_amdgcn_mfma_f32_16x16x32_bf16(af[i], bff[j], acc[i][j], 0, 0, 0);
        }
    }

    const int cn    = lane & 15;
    const int rbase = (lane >> 4) * 4;
#pragma unroll
    for (int i = 0; i < 2; i++)
#pragma unroll
        for (int j = 0; j < 4; j++) {
            int gn = n0 + wn + j * 16 + cn;
#pragma unroll
            for (int r = 0; r < 4; r++) {
                int gm = m0 + wm + i * 16 + rbase + r;
                Cf[(long)gm * C_O + gn] = acc[i][j][r];
            }
        }
}

// ---------------- per-(c,g) S + softmax -> att (bf16) ----------------
__global__ __launch_bounds__(256) void att_kernel(const float* __restrict__ e,
                                                  bf16* __restrict__ attb) {
    __shared__ float se[256][33];   // transposed: se[o][n]
    __shared__ float satt[32][33];
    const int g   = blockIdx.x;     // 0..511
    const int tid = threadIdx.x;
    const long R0 = (long)g * 32;

#pragma unroll
    for (int i = 0; i < 32; i++) se[tid][i] = e[(R0 + i) * 256 + tid];
    __syncthreads();

    {
        const int m  = tid & 31;
        const int nb = tid >> 5;
        float s0 = 0.f, s1 = 0.f, s2 = 0.f, s3 = 0.f;
        for (int o = 0; o < 256; o++) {
            float em = se[o][m];
            s0 += se[o][nb     ] * em;
            s1 += se[o][nb +  8] * em;
            s2 += se[o][nb + 16] * em;
            s3 += se[o][nb + 24] * em;
        }
        satt[nb     ][m] = s0 * (1.0f / 16.0f);
        satt[nb +  8][m] = s1 * (1.0f / 16.0f);
        satt[nb + 16][m] = s2 * (1.0f / 16.0f);
        satt[nb + 24][m] = s3 * (1.0f / 16.0f);
    }
    __syncthreads();

    if (tid < 32) {
        int n = tid;
        float mx = -1e30f;
        for (int m = 0; m < 32; m++) mx = fmaxf(mx, satt[n][m]);
        float sum = 0.f;
        for (int m = 0; m < 32; m++) { float v = __expf(satt[n][m] - mx); satt[n][m] = v; sum += v; }
        float inv = 1.0f / sum;
        for (int m = 0; m < 32; m++) satt[n][m] *= inv;
    }
    __syncthreads();

    {
        const int base = tid * 4;
        const int n = base >> 5, m = base & 31;
        bf16x4 v;
        v[0] = (bf16)satt[n][m];     v[1] = (bf16)satt[n][m + 1];
        v[2] = (bf16)satt[n][m + 2]; v[3] = (bf16)satt[n][m + 3];
        *(bf16x4*)&attb[(long)g * 1024 + base] = v;
    }
}

// ---------------- ctx = att @ X via MFMA, grid (512 groups, 8 d-chunks) ----------------
__global__ __launch_bounds__(256) void ctx_kernel(const bf16* __restrict__ attb,
                                                  const bf16* __restrict__ Xb,
                                                  bf16* __restrict__ ctx) {
    __shared__ bf16 sX[32 * 258];
    const int g   = blockIdx.x;
    const int dch = blockIdx.y;
    const int tid = threadIdx.x;
    const long R0 = (long)g * 32;
    const int d0  = dch * 256;

    {
        const int r  = tid >> 3;
        const int c0 = (tid & 7) * 32;
        const bf16* src = Xb + (R0 + r) * C_D + d0 + c0;
#pragma unroll
        for (int i = 0; i < 4; i++) {
            bf16x8 v = *(const bf16x8*)(src + i * 8);
            *(bf16x8*)&sX[r * 258 + c0 + i * 8] = v;
        }
    }
    __syncthreads();

    const int lane = tid & 63;
    const int wave = tid >> 6;
    const int rr   = lane & 15;
    const int q    = lane >> 4;

    bf16x8 af[2];
#pragma unroll
    for (int i = 0; i < 2; i++)
        af[i] = *(const bf16x8*)&attb[(long)g * 1024 + (i * 16 + rr) * 32 + q * 8];

    floatx4 acc[2][4];
#pragma unroll
    for (int i = 0; i < 2; i++)
#pragma unroll
        for (int j = 0; j < 4; j++) acc[i][j] = (floatx4){0.f, 0.f, 0.f, 0.f};

#pragma unroll
    for (int j = 0; j < 4; j++) {
        const int dl = wave * 64 + j * 16 + rr;
        bf16x8 bf_;
#pragma unroll
        for (int jj = 0; jj < 8; jj++)
            bf_[jj] = sX[(q * 8 + jj) * 258 + dl];
#pragma unroll
        for (int i = 0; i < 2; i++)
            acc[i][j] = __builtin_amdgcn_mfma_f32_16x16x32_bf16(af[i], bf_, acc[i][j], 0, 0, 0);
    }

    const int rbase = q * 4;
#pragma unroll
    for (int i = 0; i < 2; i++)
#pragma unroll
        for (int j = 0; j < 4; j++)
#pragma unroll
            for (int r = 0; r < 4; r++)
                ctx[(R0 + i * 16 + rbase + r) * C_D + d0 + wave * 64 + j * 16 + rr]
                    = (bf16)acc[i][j][r];
}

// ---------------- per-class: p_e + logits + softmax -> att2 (fused) ----------------
__global__ __launch_bounds__(256) void att2_kernel(const float* __restrict__ P,
                                                   const float* __restrict__ W2,
                                                   const float* __restrict__ fa_e,
                                                   float* __restrict__ att2f) {
    __shared__ float sp[5][C_D];    // 40 KB prototypes (fp32)
    __shared__ float spe[5][256];
    __shared__ float red[256];
    __shared__ float att[5][256];
    const int c   = blockIdx.x;
    const int tid = threadIdx.x;

    for (int t = tid; t < 5 * C_D; t += 256)
        sp[t >> 11][t & (C_D - 1)] = P[(long)c * 5 * C_D + t];
    __syncthreads();

    // p_e[p][tid] = <P[c,p,:], W2[tid,:]> / 16  (W2 fp32, L2-hot across classes)
    {
        const float4* w = (const float4*)(W2 + (long)tid * C_D);
        float acc[5] = {0.f, 0.f, 0.f, 0.f, 0.f};
        for (int k4 = 0; k4 < C_D / 4; k4++) {
            float4 wv = w[k4];
            int k = k4 * 4;
#pragma unroll
            for (int p = 0; p < 5; p++)
                acc[p] += sp[p][k] * wv.x + sp[p][k+1] * wv.y + sp[p][k+2] * wv.z + sp[p][k+3] * wv.w;
        }
#pragma unroll
        for (int p = 0; p < 5; p++) spe[p][tid] = acc[p] * (1.0f / 16.0f);
    }
    __syncthreads();

    // logits: thread = n, float4 over o
    {
        const float4* fa = (const float4*)(fa_e + ((long)c * 256 + tid) * 256);
        float acc[5] = {0.f, 0.f, 0.f, 0.f, 0.f};
        for (int o4 = 0; o4 < 64; o4++) {
            float4 f = fa[o4];
#pragma unroll
            for (int p = 0; p < 5; p++) {
                float4 s = *(const float4*)&spe[p][o4 * 4];
                acc[p] += s.x * f.x + s.y * f.y + s.z * f.z + s.w * f.w;
            }
        }
#pragma unroll
        for (int p = 0; p < 5; p++) att[p][tid] = acc[p];
    }
    __syncthreads();

    for (int p = 0; p < 5; p++) {
        float v = att[p][tid];
        red[tid] = v; __syncthreads();
        for (int s = 128; s > 0; s >>= 1) { if (tid < s) red[tid] = fmaxf(red[tid], red[tid + s]); __syncthreads(); }
        float mx = red[0]; __syncthreads();
        float ev = __expf(v - mx);
        red[tid] = ev; __syncthreads();
        for (int s = 128; s > 0; s >>= 1) { if (tid < s) red[tid] += red[tid + s]; __syncthreads(); }
        float sum = red[0]; __syncthreads();
        att2f[((long)c * 5 + p) * 256 + tid] = ev / sum;
    }
}

// ---------------- out = att2 @ Y, grid (64 classes, 8 d-chunks) x 256 ----------------
__global__ __launch_bounds__(256) void out_kernel(const float* __restrict__ att2f,
                                                  const bf16* __restrict__ Yb,
                                                  float* __restrict__ out) {
    __shared__ float s2[5][256];
    const int c   = blockIdx.x;
    const int ch  = blockIdx.y;
    const int tid = threadIdx.x;

    for (int t = tid; t < 5 * 256; t += 256)
        s2[t >> 8][t & 255] = att2f[(long)c * 5 * 256 + t];
    __syncthreads();

    const int d = ch * 256 + tid;
    const bf16* Yc = Yb + (long)c * C_O * C_D + d;
    float acc[5] = {0.f, 0.f, 0.f, 0.f, 0.f};
    for (int n4 = 0; n4 < 64; n4++) {
        float y0 = (float)Yc[(long)(n4 * 4 + 0) * C_D];
        float y1 = (float)Yc[(long)(n4 * 4 + 1) * C_D];
        float y2 = (float)Yc[(long)(n4 * 4 + 2) * C_D];
        float y3 = (float)Yc[(long)(n4 * 4 + 3) * C_D];
#pragma unroll
        for (int p = 0; p < 5; p++) {
            float4 a = *(const float4*)&s2[p][n4 * 4];
            acc[p] += a.x * y0 + a.y * y1 + a.z * y2 + a.w * y3;
        }
    }
#pragma unroll
    for (int p = 0; p < 5; p++)
        out[((long)c * 5 + p) * C_D + d] = acc[p];
}

extern "C" void kernel_launch(void* const* d_in, const int* in_sizes, int n_in,
                              void* d_out, int out_size, void* d_ws, size_t ws_size,
                              hipStream_t stream) {
    const float* X   = (const float*)d_in[0];
    const float* P   = (const float*)d_in[1];
    const float* W1  = (const float*)d_in[2];
    const float* T   = (const float*)d_in[3];
    const float* Wi1 = (const float*)d_in[4];
    const float* Wi2 = (const float*)d_in[5];
    float* out = (float*)d_out;

    char* ws = (char*)d_ws;
    size_t off = 0;
    auto alloc = [&](size_t bytes) -> void* {
        void* p = ws + off;
        off += (bytes + 255) & ~(size_t)255;
        return p;
    };
    const size_t NX = (size_t)C_M * C_D;
    bf16*  Xb   = (bf16*)alloc(NX * 2);
    bf16*  ctxb = (bf16*)alloc(NX * 2);
    bf16*  Tb   = (bf16*)alloc((size_t)C_D * C_D * 2);
    bf16*  W1b  = (bf16*)alloc((size_t)C_O * C_D * 2);
    bf16*  Wi1b = (bf16*)alloc((size_t)C_O * C_D * 2);
    bf16*  Yb   = (bf16*)alloc(NX * 2);
    float* eBuf = (float*)alloc((size_t)C_M * C_O * 4);
    bf16*  attb = (bf16*)alloc((size_t)512 * 1024 * 2);
    float* faBuf = eBuf;            // e dead after att_kernel
    float* att2f = (float*)attb;    // attb dead after ctx_kernel

    // 1. X + weights -> bf16 (single merged launch)
    const int nConv4 = (C_M * C_D + C_D * C_D + 2 * C_O * C_D) / 4;
    convw_kernel<<<nConv4 / 256, 256, 0, stream>>>(X, T, W1, Wi1, Xb, Tb, W1b, Wi1b);

    // 2. e = Xb . W1^T [16384,256]
    gemm64<<<dim3(C_M / 64, 2), 256, 0, stream>>>(Xb, W1b, eBuf);

    // 3. S + softmax -> att (bf16)
    att_kernel<<<C_CLASS * C_GROUPS, 256, 0, stream>>>(eBuf, attb);

    // 4. ctx = att @ X (batched MFMA)
    ctx_kernel<<<dim3(C_CLASS * C_GROUPS, 8), 256, 0, stream>>>(attb, Xb, ctxb);

    // 5. Y = bf16(Xb + relu(ctx . T^T))
    gemm_relu<<<(C_M / 128) * (C_D / 128), 256, 0, stream>>>(ctxb, Tb, Xb, Yb);

    // 6. fa_e = Y . Wi1^T [16384,256]
    gemm64<<<dim3(C_M / 64, 2), 256, 0, stream>>>(Yb, Wi1b, faBuf);

    // 7. fused p_e + logits + softmax -> att2
    att2_kernel<<<C_CLASS, 256, 0, stream>>>(P, Wi2, faBuf, att2f);

    // 8. out = att2 @ Y
    out_kernel<<<dim3(C_CLASS, 8), 256, 0, stream>>>(att2f, Yb, out);
}